// Round 12
// baseline (453.833 us; speedup 1.0000x reference)
//
#include <hip/hip_runtime.h>
#include <math.h>

constexpr int Bn = 256, Sn = 128, Hn = 256;
constexpr int GRP = 8;          // 8 s-rows per reduce group
constexpr int RPB = 32;         // s-rows per block
constexpr int WROWS = RPB + 16; // staged window rows (s0-8 .. s0+39)

// ---------------- setup: branch kernels k_i[h,tau] = irfft(w_i[h,:]) ----------------
// kT layout: [24][H]  slots: n=3 -> 0..2, n=5 -> 3..7, n=7 -> 8..14, n=9 -> 15..23
__global__ void k_setup(const float* __restrict__ w3, const float* __restrict__ w5,
                        const float* __restrict__ w7, const float* __restrict__ w9,
                        float* __restrict__ kT) {
  int t = blockIdx.x * blockDim.x + threadIdx.x;
  if (t >= 24 * Hn) return;
  int slot = t >> 8, h = t & 255;
  int n, base;
  const float* w;
  if (slot < 3)       { n = 3; base = 0;  w = w3; }
  else if (slot < 8)  { n = 5; base = 3;  w = w5; }
  else if (slot < 15) { n = 7; base = 8;  w = w7; }
  else                { n = 9; base = 15; w = w9; }
  int tau = slot - base;
  int F = (n + 1) / 2;
  float acc = w[(h * F) * 2];  // DC real (imag of DC cannot affect real output)
  for (int f = 1; f < F; f++) {
    float wr = w[(h * F + f) * 2 + 0];
    float wi = w[(h * F + f) * 2 + 1];
    int ft = (f * tau) % n;
    float ang = 6.28318530717958647692f * (float)ft / (float)n;
    float sv, cv;
    __sincosf(ang, &sv, &cv);
    acc += 2.f * (wr * cv - wi * sv);
  }
  kT[slot * Hn + h] = acc / (float)n;
}

// ---------------- setup: fft-branch circular kernel c[h,d] = irfft(cw[:,h]) ----------------
// cT layout: [128][H]  (d-major so lane reads over h are coalesced)
__global__ void c_setup(const float* __restrict__ cw, float* __restrict__ cT) {
  int t = blockIdx.x * blockDim.x + threadIdx.x;
  if (t >= Sn * Hn) return;
  int d = t >> 8, h = t & 255;
  float acc = cw[(0 * Hn + h) * 2 + 0] + ((d & 1) ? -1.f : 1.f) * cw[(64 * Hn + h) * 2 + 0];
  for (int k = 1; k < 64; k++) {
    float wr = cw[(k * Hn + h) * 2 + 0];
    float wi = cw[(k * Hn + h) * 2 + 1];
    int kd = (k * d) & 127;
    float ang = 6.28318530717958647692f * (float)kd * (1.f / 128.f);
    float sv, cv;
    __sincosf(ang, &sv, &cv);
    acc += 2.f * (wr * cv - wi * sv);
  }
  cT[d * Hn + h] = acc * (1.f / 128.f);
}

// ---------------- DPP wave reduction (VALU pipe, not DS) ----------------
template <int CTRL, int ROW_MASK>
__device__ __forceinline__ float dpp_add_f32(float v) {
  int p = __builtin_amdgcn_update_dpp(0, __float_as_int(v), CTRL, ROW_MASK, 0xf, true);
  return v + __int_as_float(p);
}
__device__ __forceinline__ float wave_red_sum(float v) {
  v = dpp_add_f32<0x111, 0xf>(v); // row_shr:1
  v = dpp_add_f32<0x112, 0xf>(v); // row_shr:2
  v = dpp_add_f32<0x114, 0xf>(v); // row_shr:4
  v = dpp_add_f32<0x118, 0xf>(v); // row_shr:8
  v = dpp_add_f32<0x142, 0xa>(v); // row_bcast:15
  v = dpp_add_f32<0x143, 0xc>(v); // row_bcast:31
  return v;                       // lane 63 = full wave sum
}

// ---------------- STFT branch accumulation (taps + overlap-add geometry) ----------------
template <int N, int BASE>
__device__ __attribute__((always_inline)) void branch_accum(
    const float (&xw)[GRP + 16], const float (&kreg)[24], int s0, bool edge, float (&z)[GRP]) {
  constexpr int PAD = (N - 1) / 2;
  #pragma unroll
  for (int i = 0; i < GRP; i++) z[i] = 0.f;
  #pragma unroll
  for (int j = -(N - 1); j <= N - 1; j++) {
    const int m = (((-j) % N) + N) % N;   // folded at compile time under unroll
    const float kc = kreg[BASE + m];
    if (!edge) {
      const float ka = kc * ((float)(N - (j < 0 ? -j : j)) * (1.f / (float)N));
      #pragma unroll
      for (int i = 0; i < GRP; i++) z[i] = fmaf(ka, xw[8 + i + j], z[i]);
    } else {
      #pragma unroll
      for (int i = 0; i < GRP; i++) {
        int s = s0 + i, l = s + PAD;
        int tlo = max(0, max(l - Sn + 1, -j));
        int thi = min(N - 1, min(l, N - 1 - j));
        int cnt = max(0, thi - tlo + 1);
        int elo = max(0, l - Sn + 1), ehi = min(N - 1, l);
        float env = (float)(ehi - elo + 1);
        z[i] = fmaf(kc * ((float)cnt / env), xw[8 + i + j], z[i]);
      }
    }
  }
}

// ---------------- fused main kernel: one block per (batch, 32-row chunk) ----------------
// Toolchain fact (R2/R5/R9/R10): VGPR cap = 65536/blockDim, attribute-immune.
// 512 thr -> 128-reg cap; live set ~105 fits (R8 measured 112 for same phases).
// LDS = 48K window + 0.5K red -> 3 blocks/CU = 24 waves/CU = 6 waves/SIMD
// (vs 1 block/CU = 2 waves/SIMD when staging all 128 rows). Conv reads x and cT
// from global: both L2/L3-resident, latency hidden by 6 waves/SIMD.
__global__ __launch_bounds__(512)
void stft_main(
    const float* __restrict__ x, const float* __restrict__ cT,
    const float* __restrict__ kT, const float* __restrict__ lnw,
    const float* __restrict__ lnb, const float* __restrict__ alphap,
    float* __restrict__ out) {
  __shared__ float xs[WROWS][Hn];       // 49152 B  (rows rowbase-8 .. rowbase+39)
  __shared__ float red[2][GRP][4][2];   // 512 B    cross-wave LN partials

  const int t = threadIdx.x;
  const int h = t & 255;
  const int sg = t >> 8;       // 16-row half within the chunk
  const int wv = h >> 6;       // wave within half
  const int lane = h & 63;
  const int blk = blockIdx.x;
  const int b = blk >> 2;      // 4 chunks per batch
  const int rowbase = (blk & 3) * RPB;

  // stage window rows rowbase-8 .. rowbase+39 (zero-padded outside [0,Sn))
  {
    const int base = rowbase - 8;
    #pragma unroll
    for (int c = 0; c < 6; c++) {
      int idx = c * 512 + t;          // float4 index, 64 per row
      int wr = idx >> 6, col4 = idx & 63;
      int rg = base + wr;
      float4 v = make_float4(0.f, 0.f, 0.f, 0.f);
      if (rg >= 0 && rg < Sn)
        v = ((const float4*)(x + ((size_t)b * Sn + rg) * Hn))[col4];
      ((float4*)&xs[wr][0])[col4] = v;
    }
  }
  float kreg[24];
  #pragma unroll
  for (int q = 0; q < 24; q++) kreg[q] = kT[q * Hn + h];
  const float alpha = alphap[0];
  const float wgt = lnw[h], bia = lnb[h];
  __syncthreads();

  // LN stats over h (256) for GRP s-rows; normalizes in place (no affine).
  auto reduce_ln_raw = [&](float (&q)[GRP]) {
    #pragma unroll
    for (int i = 0; i < GRP; i++) {
      float s1 = wave_red_sum(q[i]);
      float s2 = wave_red_sum(q[i] * q[i]);
      if (lane == 63) { red[sg][i][wv][0] = s1; red[sg][i][wv][1] = s2; }
    }
    __syncthreads();
    #pragma unroll
    for (int i = 0; i < GRP; i++) {
      const float4* rp = (const float4*)&red[sg][i][0][0];
      float4 p0 = rp[0], p1 = rp[1];
      float ts = p0.x + p0.z + p1.x + p1.z;
      float tq = p0.y + p0.w + p1.y + p1.w;
      float u = ts * (1.f / 256.f);
      float var = fmaf(-u, u, tq * (1.f / 256.f));
      float inv = 1.f / sqrtf(var + 1e-12f);
      q[i] = (q[i] - u) * inv;   // normalized, no affine
    }
    __syncthreads();
  };

  #pragma unroll 1   // keep rolled: unrolling inflated live ranges into scratch (R4)
  for (int g = 0; g < 2; g++) {
    const int s0 = rowbase + sg * 16 + g * GRP;   // global first row of this group
    const int w0 = sg * 16 + g * GRP + 8;         // its row in the LDS window
    const bool edge = (s0 == 0) || (s0 + GRP == Sn);

    // x window rows s0-8 .. s0+15 from LDS
    float xw[GRP + 16];
    #pragma unroll
    for (int k = 0; k < GRP + 16; k++) xw[k] = xs[w0 - 8 + k][h];

    // ---- four STFT branches, each layernormed (raw) then summed ----
    float semb[GRP];
    {
      float z[GRP];
      branch_accum<3, 0>(xw, kreg, s0, edge, z);
      reduce_ln_raw(z);
      #pragma unroll
      for (int i = 0; i < GRP; i++) semb[i] = z[i];
      branch_accum<5, 3>(xw, kreg, s0, edge, z);
      reduce_ln_raw(z);
      #pragma unroll
      for (int i = 0; i < GRP; i++) semb[i] += z[i];
      branch_accum<7, 8>(xw, kreg, s0, edge, z);
      reduce_ln_raw(z);
      #pragma unroll
      for (int i = 0; i < GRP; i++) semb[i] += z[i];
      branch_accum<9, 15>(xw, kreg, s0, edge, z);
      reduce_ln_raw(z);
      #pragma unroll
      for (int i = 0; i < GRP; i++) semb[i] += z[i];
    }

    // ---- global-fft branch: circular conv, 8x16 Toeplitz tiles, x/cT from L2 ----
    float ff[GRP];
    #pragma unroll
    for (int i = 0; i < GRP; i++) ff[i] = 0.f;
    const float* xb = x + (size_t)b * Sn * Hn + h;
    #pragma unroll 1   // keep rolled: bounds the cd/xr live window
    for (int rt = 0; rt < 8; rt++) {
      const int r0 = rt * 16;
      const int dbase = (s0 - r0) & 127;
      float cd[GRP + 15];
      #pragma unroll
      for (int k = 0; k < GRP + 15; k++)
        cd[k] = cT[((dbase + k - 15) & 127) * Hn + h];
      float xr[16];
      #pragma unroll
      for (int j = 0; j < 16; j++) xr[j] = xb[(r0 + j) * Hn];
      #pragma unroll
      for (int i = 0; i < GRP; i++) {
        #pragma unroll
        for (int j = 0; j < 16; j++)
          ff[i] = fmaf(cd[i - j + 15], xr[j], ff[i]);
      }
    }
    reduce_ln_raw(ff);

    // ---- mix + residual + final LN + store ----
    // sum_i LN_i = w*S + 4b ; LN_fft = w*F + b
    // mixed = w*(alpha*S + (1-alpha)*F) + b*(1+3*alpha) + x
    float fin[GRP];
    #pragma unroll
    for (int i = 0; i < GRP; i++) {
      float mixv = fmaf(alpha, semb[i] - ff[i], ff[i]);   // alpha*S + (1-alpha)*F
      fin[i] = fmaf(wgt, mixv, fmaf(3.f * alpha + 1.f, bia, xs[w0 + i][h]));
    }
    reduce_ln_raw(fin);
    #pragma unroll
    for (int i = 0; i < GRP; i++)
      out[((size_t)b * Sn + (s0 + i)) * Hn + h] = fmaf(fin[i], wgt, bia);
  }
}

extern "C" void kernel_launch(void* const* d_in, const int* in_sizes, int n_in,
                              void* d_out, int out_size, void* d_ws, size_t ws_size,
                              hipStream_t stream) {
  const float* x  = (const float*)d_in[0];
  const float* w3 = (const float*)d_in[1];
  const float* w5 = (const float*)d_in[2];
  const float* w7 = (const float*)d_in[3];
  const float* w9 = (const float*)d_in[4];
  const float* cw = (const float*)d_in[5];
  const float* al = (const float*)d_in[6];
  const float* lw = (const float*)d_in[7];
  const float* lb = (const float*)d_in[8];
  float* out = (float*)d_out;

  float* cT = (float*)d_ws;        // 128*256 floats
  float* kT = cT + Sn * Hn;        // 24*256 floats

  hipLaunchKernelGGL(k_setup, dim3(24), dim3(256), 0, stream, w3, w5, w7, w9, kT);
  hipLaunchKernelGGL(c_setup, dim3(Sn), dim3(256), 0, stream, cw, cT);
  hipLaunchKernelGGL(stft_main, dim3(Bn * 4), dim3(512), 0, stream, x, cT, kT, lw, lb, al, out);
}

// Round 13
// 319.575 us; speedup vs baseline: 1.4201x; 1.4201x over previous
//
#include <hip/hip_runtime.h>
#include <math.h>

constexpr int Bn = 256, Sn = 128, Hn = 256;
constexpr int GRP = 8;          // 8 s-rows per reduce group
constexpr int RPB = 32;         // s-rows per block
constexpr int WROWS = RPB + 16; // staged window rows (rowbase-8 .. rowbase+39)

// ---------------- setup: branch kernels k_i[h,tau] = irfft(w_i[h,:]) ----------------
// kT layout: [24][H]  slots: n=3 -> 0..2, n=5 -> 3..7, n=7 -> 8..14, n=9 -> 15..23
__global__ void k_setup(const float* __restrict__ w3, const float* __restrict__ w5,
                        const float* __restrict__ w7, const float* __restrict__ w9,
                        float* __restrict__ kT) {
  int t = blockIdx.x * blockDim.x + threadIdx.x;
  if (t >= 24 * Hn) return;
  int slot = t >> 8, h = t & 255;
  int n, base;
  const float* w;
  if (slot < 3)       { n = 3; base = 0;  w = w3; }
  else if (slot < 8)  { n = 5; base = 3;  w = w5; }
  else if (slot < 15) { n = 7; base = 8;  w = w7; }
  else                { n = 9; base = 15; w = w9; }
  int tau = slot - base;
  int F = (n + 1) / 2;
  float acc = w[(h * F) * 2];  // DC real (imag of DC cannot affect real output)
  for (int f = 1; f < F; f++) {
    float wr = w[(h * F + f) * 2 + 0];
    float wi = w[(h * F + f) * 2 + 1];
    int ft = (f * tau) % n;
    float ang = 6.28318530717958647692f * (float)ft / (float)n;
    float sv, cv;
    __sincosf(ang, &sv, &cv);
    acc += 2.f * (wr * cv - wi * sv);
  }
  kT[slot * Hn + h] = acc / (float)n;
}

// ---------------- setup: fft-branch circular kernel c[h,d] = irfft(cw[:,h]) ----------------
// cT layout: [128][H]  (d-major so lane reads over h are coalesced)
__global__ void c_setup(const float* __restrict__ cw, float* __restrict__ cT) {
  int t = blockIdx.x * blockDim.x + threadIdx.x;
  if (t >= Sn * Hn) return;
  int d = t >> 8, h = t & 255;
  float acc = cw[(0 * Hn + h) * 2 + 0] + ((d & 1) ? -1.f : 1.f) * cw[(64 * Hn + h) * 2 + 0];
  for (int k = 1; k < 64; k++) {
    float wr = cw[(k * Hn + h) * 2 + 0];
    float wi = cw[(k * Hn + h) * 2 + 1];
    int kd = (k * d) & 127;
    float ang = 6.28318530717958647692f * (float)kd * (1.f / 128.f);
    float sv, cv;
    __sincosf(ang, &sv, &cv);
    acc += 2.f * (wr * cv - wi * sv);
  }
  cT[d * Hn + h] = acc * (1.f / 128.f);
}

// ---------------- DPP wave reduction (VALU pipe, not DS) ----------------
template <int CTRL, int ROW_MASK>
__device__ __forceinline__ float dpp_add_f32(float v) {
  int p = __builtin_amdgcn_update_dpp(0, __float_as_int(v), CTRL, ROW_MASK, 0xf, true);
  return v + __int_as_float(p);
}
__device__ __forceinline__ float wave_red_sum(float v) {
  v = dpp_add_f32<0x111, 0xf>(v); // row_shr:1
  v = dpp_add_f32<0x112, 0xf>(v); // row_shr:2
  v = dpp_add_f32<0x114, 0xf>(v); // row_shr:4
  v = dpp_add_f32<0x118, 0xf>(v); // row_shr:8
  v = dpp_add_f32<0x142, 0xa>(v); // row_bcast:15
  v = dpp_add_f32<0x143, 0xc>(v); // row_bcast:31
  return v;                       // lane 63 = full wave sum
}

// ---------------- STFT branch accumulation (taps + overlap-add geometry) ----------------
// Taps from LDS (kTs) — R8/R12 A/B proved keeping them in VGPRs overflows the
// 128-reg cap (live set >128 -> scratch spills); LDS version measured 112 regs.
template <int N, int BASE>
__device__ __attribute__((always_inline)) void branch_accum(
    const float (&xw)[GRP + 16], const float (&kTs)[24][Hn], int h,
    int s0, bool edge, float (&z)[GRP]) {
  constexpr int PAD = (N - 1) / 2;
  #pragma unroll
  for (int i = 0; i < GRP; i++) z[i] = 0.f;
  #pragma unroll
  for (int j = -(N - 1); j <= N - 1; j++) {
    const int m = (((-j) % N) + N) % N;   // folded at compile time under unroll
    const float kc = kTs[BASE + m][h];    // LDS h-stride-1, conflict-free
    if (!edge) {
      const float ka = kc * ((float)(N - (j < 0 ? -j : j)) * (1.f / (float)N));
      #pragma unroll
      for (int i = 0; i < GRP; i++) z[i] = fmaf(ka, xw[8 + i + j], z[i]);
    } else {
      #pragma unroll
      for (int i = 0; i < GRP; i++) {
        int s = s0 + i, l = s + PAD;
        int tlo = max(0, max(l - Sn + 1, -j));
        int thi = min(N - 1, min(l, N - 1 - j));
        int cnt = max(0, thi - tlo + 1);
        int elo = max(0, l - Sn + 1), ehi = min(N - 1, l);
        float env = (float)(ehi - elo + 1);
        z[i] = fmaf(kc * ((float)cnt / env), xw[8 + i + j], z[i]);
      }
    }
  }
}

// ---------------- fused main kernel: one block per (batch, 32-row chunk) ----------------
// Toolchain fact (R2/R5/R9/R10): VGPR cap = 65536/blockDim, attribute-immune.
// 512 thr -> 128-reg cap. kTs in LDS keeps the live set at R8's measured 112.
// LDS = 48K window + 24K kTs + 0.5K red = 72.5K -> 2 blocks/CU = 4 waves/SIMD
// (R8 was 1 block/CU = 2 waves/SIMD at 51% VALUBusy). Conv reads x and cT from
// global: x (33MB) is L3-resident, cT (128KB) L2-resident; latency hidden by TLP.
__global__ __launch_bounds__(512)
void stft_main(
    const float* __restrict__ x, const float* __restrict__ cT,
    const float* __restrict__ kT, const float* __restrict__ lnw,
    const float* __restrict__ lnb, const float* __restrict__ alphap,
    float* __restrict__ out) {
  __shared__ float xs[WROWS][Hn];       // 49152 B  (rows rowbase-8 .. rowbase+39)
  __shared__ float kTs[24][Hn];         // 24576 B
  __shared__ float red[2][GRP][4][2];   // 512 B    cross-wave LN partials

  const int t = threadIdx.x;
  const int h = t & 255;
  const int sg = t >> 8;       // 16-row half within the chunk
  const int wv = h >> 6;       // wave within half
  const int lane = h & 63;
  const int blk = blockIdx.x;
  const int b = blk >> 2;      // 4 chunks per batch
  const int rowbase = (blk & 3) * RPB;

  // stage window rows rowbase-8 .. rowbase+39 (zero-padded outside [0,Sn))
  {
    const int base = rowbase - 8;
    #pragma unroll
    for (int c = 0; c < 6; c++) {
      int idx = c * 512 + t;          // float4 index, 64 per row
      int wr = idx >> 6, col4 = idx & 63;
      int rg = base + wr;
      float4 v = make_float4(0.f, 0.f, 0.f, 0.f);
      if (rg >= 0 && rg < Sn)
        v = ((const float4*)(x + ((size_t)b * Sn + rg) * Hn))[col4];
      ((float4*)&xs[wr][0])[col4] = v;
    }
  }
  // stage kT into LDS (1536 float4, 3 per thread)
  {
    const float4* kg = (const float4*)kT;
    float4* kl = (float4*)(&kTs[0][0]);
    #pragma unroll
    for (int c = 0; c < 3; c++) kl[c * 512 + t] = kg[c * 512 + t];
  }
  const float alpha = alphap[0];
  const float wgt = lnw[h], bia = lnb[h];
  __syncthreads();

  // LN stats over h (256) for GRP s-rows; normalizes in place (no affine).
  auto reduce_ln_raw = [&](float (&q)[GRP]) {
    #pragma unroll
    for (int i = 0; i < GRP; i++) {
      float s1 = wave_red_sum(q[i]);
      float s2 = wave_red_sum(q[i] * q[i]);
      if (lane == 63) { red[sg][i][wv][0] = s1; red[sg][i][wv][1] = s2; }
    }
    __syncthreads();
    #pragma unroll
    for (int i = 0; i < GRP; i++) {
      const float4* rp = (const float4*)&red[sg][i][0][0];
      float4 p0 = rp[0], p1 = rp[1];
      float ts = p0.x + p0.z + p1.x + p1.z;
      float tq = p0.y + p0.w + p1.y + p1.w;
      float u = ts * (1.f / 256.f);
      float var = fmaf(-u, u, tq * (1.f / 256.f));
      float inv = 1.f / sqrtf(var + 1e-12f);
      q[i] = (q[i] - u) * inv;   // normalized, no affine
    }
    __syncthreads();
  };

  #pragma unroll 1   // keep rolled: unrolling inflated live ranges into scratch (R4)
  for (int g = 0; g < 2; g++) {
    const int s0 = rowbase + sg * 16 + g * GRP;   // global first row of this group
    const int w0 = sg * 16 + g * GRP + 8;         // its row in the LDS window
    const bool edge = (s0 == 0) || (s0 + GRP == Sn);

    // x window rows s0-8 .. s0+15 from LDS
    float xw[GRP + 16];
    #pragma unroll
    for (int k = 0; k < GRP + 16; k++) xw[k] = xs[w0 - 8 + k][h];

    // ---- four STFT branches, each layernormed (raw) then summed ----
    float semb[GRP];
    {
      float z[GRP];
      branch_accum<3, 0>(xw, kTs, h, s0, edge, z);
      reduce_ln_raw(z);
      #pragma unroll
      for (int i = 0; i < GRP; i++) semb[i] = z[i];
      branch_accum<5, 3>(xw, kTs, h, s0, edge, z);
      reduce_ln_raw(z);
      #pragma unroll
      for (int i = 0; i < GRP; i++) semb[i] += z[i];
      branch_accum<7, 8>(xw, kTs, h, s0, edge, z);
      reduce_ln_raw(z);
      #pragma unroll
      for (int i = 0; i < GRP; i++) semb[i] += z[i];
      branch_accum<9, 15>(xw, kTs, h, s0, edge, z);
      reduce_ln_raw(z);
      #pragma unroll
      for (int i = 0; i < GRP; i++) semb[i] += z[i];
    }

    // ---- global-fft branch: circular conv, 8x16 Toeplitz tiles, x/cT from L2/L3 ----
    float ff[GRP];
    #pragma unroll
    for (int i = 0; i < GRP; i++) ff[i] = 0.f;
    const float* xb = x + (size_t)b * Sn * Hn + h;
    #pragma unroll 1   // keep rolled: bounds the cd/xr live window
    for (int rt = 0; rt < 8; rt++) {
      const int r0 = rt * 16;
      const int dbase = (s0 - r0) & 127;
      float cd[GRP + 15];
      #pragma unroll
      for (int k = 0; k < GRP + 15; k++)
        cd[k] = cT[((dbase + k - 15) & 127) * Hn + h];
      float xr[16];
      #pragma unroll
      for (int j = 0; j < 16; j++) xr[j] = xb[(r0 + j) * Hn];
      #pragma unroll
      for (int i = 0; i < GRP; i++) {
        #pragma unroll
        for (int j = 0; j < 16; j++)
          ff[i] = fmaf(cd[i - j + 15], xr[j], ff[i]);
      }
    }
    reduce_ln_raw(ff);

    // ---- mix + residual + final LN + store ----
    // sum_i LN_i = w*S + 4b ; LN_fft = w*F + b
    // mixed = w*(alpha*S + (1-alpha)*F) + b*(1+3*alpha) + x
    float fin[GRP];
    #pragma unroll
    for (int i = 0; i < GRP; i++) {
      float mixv = fmaf(alpha, semb[i] - ff[i], ff[i]);   // alpha*S + (1-alpha)*F
      fin[i] = fmaf(wgt, mixv, fmaf(3.f * alpha + 1.f, bia, xs[w0 + i][h]));
    }
    reduce_ln_raw(fin);
    #pragma unroll
    for (int i = 0; i < GRP; i++)
      out[((size_t)b * Sn + (s0 + i)) * Hn + h] = fmaf(fin[i], wgt, bia);
  }
}

extern "C" void kernel_launch(void* const* d_in, const int* in_sizes, int n_in,
                              void* d_out, int out_size, void* d_ws, size_t ws_size,
                              hipStream_t stream) {
  const float* x  = (const float*)d_in[0];
  const float* w3 = (const float*)d_in[1];
  const float* w5 = (const float*)d_in[2];
  const float* w7 = (const float*)d_in[3];
  const float* w9 = (const float*)d_in[4];
  const float* cw = (const float*)d_in[5];
  const float* al = (const float*)d_in[6];
  const float* lw = (const float*)d_in[7];
  const float* lb = (const float*)d_in[8];
  float* out = (float*)d_out;

  float* cT = (float*)d_ws;        // 128*256 floats
  float* kT = cT + Sn * Hn;        // 24*256 floats

  hipLaunchKernelGGL(k_setup, dim3(24), dim3(256), 0, stream, w3, w5, w7, w9, kT);
  hipLaunchKernelGGL(c_setup, dim3(Sn), dim3(256), 0, stream, cw, cT);
  hipLaunchKernelGGL(stft_main, dim3(Bn * 4), dim3(512), 0, stream, x, cT, kT, lw, lb, al, out);
}